// Round 1
// 1596.490 us; speedup vs baseline: 2.3923x; 2.3923x over previous
//
#include <hip/hip_runtime.h>

#define NTOK 49
#define CDIM 96
#define NH   3
#define HD   32

typedef __bf16 bf16x8 __attribute__((ext_vector_type(8)));
typedef float f32x4 __attribute__((ext_vector_type(4)));
typedef short short8 __attribute__((ext_vector_type(8)));

__device__ __forceinline__ unsigned short f2bf(float f) {
  union { float f; unsigned u; } v; v.f = f;
  unsigned r = v.u + 0x7FFFu + ((v.u >> 16) & 1u);   // RNE
  return (unsigned short)(r >> 16);
}
__device__ __forceinline__ float bf2f(unsigned short h) {
  union { unsigned u; float f; } v; v.u = ((unsigned)h) << 16;
  return v.f;
}

// ---------------------------------------------------------------------------
// Prep kernel: fp32 weights in -> fused/transposed bf16 weights in d_ws.
//   [     0..27648)  W1cat_t [288][96] = [wq_sp | wk_sp | wv]^T
//   [ 27648..46080)  W2cat_t [192][96] = per-head [q|k] slices of wq,wk
//   [ 46080..55296)  W1b_t   [96][96]  = (w_ps @ Wp_top)^T
//   [ 55296..64512)  W2b_t   [96][96]  = (w_pc @ Wp_bot)^T
//   [ 64512..73728)  Wpb_t   [96][96]  = Wp_bot^T
//   float[96] @ byte 147456: bias_all = b_ps@Wp_top + b_pc@Wp_bot + b_proj
// ---------------------------------------------------------------------------
__global__ void prep_weights(const float* __restrict__ wq,
                             const float* __restrict__ wk,
                             const float* __restrict__ wv,
                             const float* __restrict__ wq_sp,
                             const float* __restrict__ wk_sp,
                             const float* __restrict__ w_ps,
                             const float* __restrict__ b_ps,
                             const float* __restrict__ w_pc,
                             const float* __restrict__ b_pc,
                             const float* __restrict__ w_proj,
                             const float* __restrict__ b_proj,
                             unsigned short* __restrict__ wsS,
                             float* __restrict__ wsB)
{
  const int g0 = blockIdx.x * blockDim.x + threadIdx.x;
  const int gs = gridDim.x * blockDim.x;
  const int TOT = 73728 + 96;
  for (int idx = g0; idx < TOT; idx += gs) {
    if (idx < 27648) {
      int o = idx / 96, i = idx % 96;
      float v;
      if (o < 96)       v = wq_sp[i*96 + o];
      else if (o < 192) v = wk_sp[i*96 + (o-96)];
      else              v = wv  [i*96 + (o-192)];
      wsS[idx] = f2bf(v);
    } else if (idx < 46080) {
      int j = idx - 27648, o = j / 96, i = j % 96;
      int h = o >> 6, cc = o & 63;
      wsS[idx] = f2bf((cc < 32) ? wq[i*96 + h*32 + cc] : wk[i*96 + h*32 + (cc-32)]);
    } else if (idx < 55296) {
      int j = idx - 46080, o = j / 96, i = j % 96;
      float a = 0.f;
      for (int k = 0; k < 96; ++k) a += w_ps[i*96+k] * w_proj[k*96+o];
      wsS[idx] = f2bf(a);
    } else if (idx < 64512) {
      int j = idx - 55296, o = j / 96, i = j % 96;
      float a = 0.f;
      for (int k = 0; k < 96; ++k) a += w_pc[i*96+k] * w_proj[(96+k)*96+o];
      wsS[idx] = f2bf(a);
    } else if (idx < 73728) {
      int j = idx - 64512, o = j / 96, i = j % 96;
      wsS[idx] = f2bf(w_proj[(96+i)*96 + o]);
    } else {
      int o = idx - 73728;
      float a = b_proj[o];
      for (int k = 0; k < 96; ++k) {
        a += b_ps[k] * w_proj[k*96+o];
        a += b_pc[k] * w_proj[(96+k)*96+o];
      }
      wsB[o] = a;
    }
  }
}

// ---------------------------------------------------------------------------
// Fused window kernel. GEMM-shaped stages (B, I, J, K) now use
// v_mfma_f32_16x16x32_bf16: wave w owns token m-tile w (tokens 16w..16w+15),
// weights are consumed as B-fragments directly from L2-resident bf16 tables.
// Fragment layout: A/B lane l supplies row (l&15), k = (l>>4)*8 + j (one
// contiguous 16B read); D lane l holds rows (l>>4)*4+r, col (l&15) [measured].
// m-tile 3 rows 49..63 read garbage (in-allocation) and are write-guarded.
// VALU stages C/D/E/F/G/H unchanged from the verified round-3 kernel.
// LDS slots (bf16 shorts):
//   X  [49][96] @0      : input window (never overwritten)
//   V  [49][96] @4704   : v_inp
//   QS [49][96] @9408   : qs -> xc
//   KS [49][96] @14112  : ks -> gelu(conv1) -> out_p
//   Q  [49][96] @18816  : q (all heads) -> sp (per head, in place)
//   K  [49][96] @23520  : k (all heads)
//   SC 4096     @28224  : cattn [96][32] then scores/probs [49..64][64]
//                         (cols 49..63 zeroed so padded K=64 PV is exact)
// ---------------------------------------------------------------------------
__global__ __launch_bounds__(256, 2) void winattn_mfma(
    const float* __restrict__ x,
    const float* __restrict__ rpb,      // [169][3]
    const float* __restrict__ bq,
    const float* __restrict__ bk,
    const float* __restrict__ bv,
    const float* __restrict__ conv1w,   // [9][96]
    const float* __restrict__ conv2w,   // [9][96]
    const unsigned short* __restrict__ wcat1,    // [288][96] bf16
    const unsigned short* __restrict__ wcat2,    // [192][96] bf16
    const unsigned short* __restrict__ w1b,      // [96][96] bf16
    const unsigned short* __restrict__ w2b,      // [96][96] bf16
    const unsigned short* __restrict__ wpb,      // [96][96] bf16
    const float* __restrict__ bias_all,          // [96]
    float* __restrict__ out)
{
  __shared__ __align__(16) unsigned short sm[32320];   // 64640 B (2 blocks/CU)
  const int tid = threadIdx.x;
  const int blk = blockIdx.x;
  enum { X_O = 0, V_O = 4704, QS_O = 9408, KS_O = 14112,
         Q_O = 18816, K_O = 23520, SC_O = 28224 };
  const float SCALE = 0.17677669529663687f;

  const int w  = tid >> 6;    // wave id = token m-tile
  const int l  = tid & 63;
  const int lr = l & 15;      // fragment row / col index
  const int lg = l >> 4;      // lane group (k-slice / D row group)

  // ---- load x (fp32 -> bf16 LDS) ----
  {
    const float* xg = x + (size_t)blk * 4704;
    for (int i = tid; i < 1176; i += 256) {          // 1176*4 = 4704 floats
      const float4 v = *(const float4*)&xg[i*4];
      union { unsigned short s[4]; uint2 u; } p;
      p.s[0] = f2bf(v.x); p.s[1] = f2bf(v.y); p.s[2] = f2bf(v.z); p.s[3] = f2bf(v.w);
      *(uint2*)&sm[X_O + i*4] = p.u;
    }
  }
  __syncthreads();

  // ---- B (MFMA): [qs|ks|v] = x @ Wcat1 (+bv on v) ----
  {
    const int xrow = X_O + (16*w + lr)*96 + lg*8;
    const bf16x8 a0 = *(const bf16x8*)&sm[xrow];
    const bf16x8 a1 = *(const bf16x8*)&sm[xrow + 32];
    const bf16x8 a2 = *(const bf16x8*)&sm[xrow + 64];
    for (int t = 0; t < 18; ++t) {
      const int c = 16*t + lr;                       // output channel 0..287
      const bf16x8 b0 = *(const bf16x8*)&wcat1[c*96 + lg*8];
      const bf16x8 b1 = *(const bf16x8*)&wcat1[c*96 + 32 + lg*8];
      const bf16x8 b2 = *(const bf16x8*)&wcat1[c*96 + 64 + lg*8];
      f32x4 acc = {0.f, 0.f, 0.f, 0.f};
      acc = __builtin_amdgcn_mfma_f32_16x16x32_bf16(a0, b0, acc, 0, 0, 0);
      acc = __builtin_amdgcn_mfma_f32_16x16x32_bf16(a1, b1, acc, 0, 0, 0);
      acc = __builtin_amdgcn_mfma_f32_16x16x32_bf16(a2, b2, acc, 0, 0, 0);
      const float bias = (t >= 12) ? bv[c - 192] : 0.0f;
      const int dst = (t < 6) ? (QS_O + c) : (t < 12) ? (KS_O + c - 96) : (V_O + c - 192);
      #pragma unroll
      for (int r = 0; r < 4; ++r) {
        const int tok = 16*w + lg*4 + r;
        if (tok < NTOK) sm[dst + tok*96] = f2bf(acc[r] + bias);
      }
    }
  }
  __syncthreads();

  // ---- C: L2-normalize qs, ks along tokens (per channel) ----
  if (tid < 192) {
    const int base = (tid < 96) ? QS_O : KS_O;
    const int c    = (tid < 96) ? tid : tid - 96;
    float ss = 0.f;
    for (int n = 0; n < NTOK; ++n) { float v = bf2f(sm[base + n*96 + c]); ss += v*v; }
    const float rn = 1.0f / fmaxf(sqrtf(ss), 1e-12f);
    for (int n = 0; n < NTOK; ++n)
      sm[base + n*96 + c] = f2bf(bf2f(sm[base + n*96 + c]) * rn);
  }
  __syncthreads();

  // ---- D: cattn logits [96][32] -> SC ----
  for (int idx = tid; idx < 96*32; idx += 256) {
    const int dq = idx >> 5, e = idx & 31, h = dq >> 5;
    float a = 0.f;
    for (int n = 0; n < NTOK; ++n)
      a += bf2f(sm[KS_O + n*96 + dq]) * bf2f(sm[QS_O + n*96 + h*32 + e]);
    sm[SC_O + dq*32 + e] = f2bf(a * SCALE);
  }
  __syncthreads();

  // ---- E: softmax over e (96 rows of 32) ----
  if (tid < 96) {
    float m = -1e30f;
    for (int e = 0; e < 32; ++e) m = fmaxf(m, bf2f(sm[SC_O + tid*32 + e]));
    float s = 0.f;
    for (int e = 0; e < 32; ++e) s += __expf(bf2f(sm[SC_O + tid*32 + e]) - m);
    const float inv = 1.0f / s;
    for (int e = 0; e < 32; ++e)
      sm[SC_O + tid*32 + e] = f2bf(__expf(bf2f(sm[SC_O + tid*32 + e]) - m) * inv);
  }
  __syncthreads();

  // ---- F: xc[n][dq] = sum_e cattn[dq][e]*V[n][h*32+e] -> QS (qs dead) ----
  for (int idx = tid; idx < NTOK*96; idx += 256) {
    const int n = idx / 96, dq = idx % 96, h = dq >> 5;
    float a = 0.f;
    for (int e = 0; e < 32; ++e)
      a += bf2f(sm[SC_O + dq*32 + e]) * bf2f(sm[V_O + n*96 + h*32 + e]);
    sm[QS_O + n*96 + dq] = f2bf(a);
  }
  // ---- G: conv1 + exact GELU -> KS (ks dead; disjoint from F) ----
  for (int idx = tid; idx < NTOK*96; idx += 256) {
    const int n = idx / 96, c = idx % 96, y = n / 7, xx = n % 7;
    float a = 0.f;
    #pragma unroll
    for (int dy = -1; dy <= 1; ++dy) {
      const int yy = y + dy;
      if (yy < 0 || yy >= 7) continue;
      #pragma unroll
      for (int dx = -1; dx <= 1; ++dx) {
        const int x2 = xx + dx;
        if (x2 < 0 || x2 >= 7) continue;
        a += bf2f(sm[V_O + (yy*7+x2)*96 + c]) * conv1w[((dy+1)*3+(dx+1))*96 + c];
      }
    }
    a = 0.5f * a * (1.0f + erff(a * 0.70710678118654752f));
    sm[KS_O + idx] = f2bf(a);
  }
  __syncthreads();

  // ---- H: conv2 -> regs -> KS ----
  {
    float ov[19];
    #pragma unroll
    for (int it = 0; it < 19; ++it) {
      const int e = tid + it*256;
      float a = 0.f;
      if (e < 4704) {
        const int n = e / 96, c = e % 96, y = n / 7, xx = n % 7;
        #pragma unroll
        for (int dy = -1; dy <= 1; ++dy) {
          const int yy = y + dy;
          if (yy < 0 || yy >= 7) continue;
          #pragma unroll
          for (int dx = -1; dx <= 1; ++dx) {
            const int x2 = xx + dx;
            if (x2 < 0 || x2 >= 7) continue;
            a += bf2f(sm[KS_O + (yy*7+x2)*96 + c]) * conv2w[((dy+1)*3+(dx+1))*96 + c];
          }
        }
      }
      ov[it] = a;
    }
    __syncthreads();
    #pragma unroll
    for (int it = 0; it < 19; ++it) {
      const int e = tid + it*256;
      if (e < 4704) sm[KS_O + e] = f2bf(ov[it]);
    }
  }
  __syncthreads();

  // ---- I (MFMA): q,k = x @ Wcat2 (+bq,bk) -> Q,K slots ----
  {
    const int xrow = X_O + (16*w + lr)*96 + lg*8;
    const bf16x8 a0 = *(const bf16x8*)&sm[xrow];
    const bf16x8 a1 = *(const bf16x8*)&sm[xrow + 32];
    const bf16x8 a2 = *(const bf16x8*)&sm[xrow + 64];
    for (int t = 0; t < 12; ++t) {
      const int c = 16*t + lr;                       // wcat2 row 0..191
      const bf16x8 b0 = *(const bf16x8*)&wcat2[c*96 + lg*8];
      const bf16x8 b1 = *(const bf16x8*)&wcat2[c*96 + 32 + lg*8];
      const bf16x8 b2 = *(const bf16x8*)&wcat2[c*96 + 64 + lg*8];
      f32x4 acc = {0.f, 0.f, 0.f, 0.f};
      acc = __builtin_amdgcn_mfma_f32_16x16x32_bf16(a0, b0, acc, 0, 0, 0);
      acc = __builtin_amdgcn_mfma_f32_16x16x32_bf16(a1, b1, acc, 0, 0, 0);
      acc = __builtin_amdgcn_mfma_f32_16x16x32_bf16(a2, b2, acc, 0, 0, 0);
      const int h  = t >> 2;                         // head (uniform per tile)
      const int cc = 16*(t & 3) + lr;                // 0..63 within head
      const bool isq = (t & 2) == 0;                 // cc<32 <=> q half
      const float bias = isq ? bq[h*32 + cc] : bk[h*32 + cc - 32];
      const int dst = isq ? (Q_O + h*32 + cc) : (K_O + h*32 + cc - 32);
      #pragma unroll
      for (int r = 0; r < 4; ++r) {
        const int tok = 16*w + lg*4 + r;
        if (tok < NTOK) sm[dst + tok*96] = f2bf(acc[r] + bias);
      }
    }
  }
  __syncthreads();

  // ---- zero probs pad cols 49..63 (rows<49) so padded K=64 PV is exact ----
  for (int idx = tid; idx < NTOK*15; idx += 256) {
    const int r2 = idx / 15, c2 = 49 + idx % 15;
    sm[SC_O + r2*64 + c2] = 0;
  }

  // ---- J: spatial attention per head (QK^T and PV on MFMA) ----
  for (int h = 0; h < NH; ++h) {
    {
      const bf16x8 aq = *(const bf16x8*)&sm[Q_O + (16*w + lr)*96 + h*32 + lg*8];
      #pragma unroll
      for (int nt = 0; nt < 4; ++nt) {
        const bf16x8 bk8 = *(const bf16x8*)&sm[K_O + (16*nt + lr)*96 + h*32 + lg*8];
        f32x4 acc = {0.f, 0.f, 0.f, 0.f};
        acc = __builtin_amdgcn_mfma_f32_16x16x32_bf16(aq, bk8, acc, 0, 0, 0);
        #pragma unroll
        for (int r = 0; r < 4; ++r) {
          const int row = 16*w + lg*4 + r;           // q token
          const int col = 16*nt + lr;                // k token
          if (row < NTOK && col < NTOK) {
            const int ridx = (row/7 - col/7 + 6)*13 + (row%7 - col%7 + 6);
            sm[SC_O + row*64 + col] = f2bf(acc[r] * SCALE + rpb[ridx*NH + h]);
          }
        }
      }
    }
    __syncthreads();
    if (tid < NTOK) {
      float m = -1e30f;
      for (int j = 0; j < NTOK; ++j) m = fmaxf(m, bf2f(sm[SC_O + tid*64 + j]));
      float s = 0.f;
      for (int j = 0; j < NTOK; ++j) s += __expf(bf2f(sm[SC_O + tid*64 + j]) - m);
      const float inv = 1.0f / s;
      for (int j = 0; j < NTOK; ++j)
        sm[SC_O + tid*64 + j] = f2bf(__expf(bf2f(sm[SC_O + tid*64 + j]) - m) * inv);
    }
    __syncthreads();
    {
      const bf16x8 ap0 = *(const bf16x8*)&sm[SC_O + (16*w + lr)*64 + lg*8];
      const bf16x8 ap1 = *(const bf16x8*)&sm[SC_O + (16*w + lr)*64 + 32 + lg*8];
      #pragma unroll
      for (int nt = 0; nt < 2; ++nt) {
        f32x4 acc = {0.f, 0.f, 0.f, 0.f};
        #pragma unroll
        for (int ks = 0; ks < 2; ++ks) {
          union { short8 s; bf16x8 b; } cv;
          #pragma unroll
          for (int j = 0; j < 8; ++j)
            cv.s[j] = (short)sm[V_O + (ks*32 + lg*8 + j)*96 + h*32 + 16*nt + lr];
          acc = __builtin_amdgcn_mfma_f32_16x16x32_bf16(ks ? ap1 : ap0, cv.b, acc, 0, 0, 0);
        }
        #pragma unroll
        for (int r = 0; r < 4; ++r) {
          const int tok = 16*w + lg*4 + r;
          if (tok < NTOK) sm[Q_O + tok*96 + h*32 + 16*nt + lr] = f2bf(acc[r]);  // sp_h over q_h
        }
      }
    }
    __syncthreads();
  }

  // ---- K (MFMA): out = sp@W1b + xc@W2b + outp@Wpb + bias_all (fp32 store) ----
  {
    f32x4 acc[6];
    #pragma unroll
    for (int t = 0; t < 6; ++t) acc[t] = (f32x4){0.f, 0.f, 0.f, 0.f};
    const int Ao[3] = { Q_O, QS_O, KS_O };
    const unsigned short* const Ws[3] = { w1b, w2b, wpb };
    #pragma unroll
    for (int s = 0; s < 3; ++s) {
      const int arow = Ao[s] + (16*w + lr)*96 + lg*8;
      const bf16x8 a0 = *(const bf16x8*)&sm[arow];
      const bf16x8 a1 = *(const bf16x8*)&sm[arow + 32];
      const bf16x8 a2 = *(const bf16x8*)&sm[arow + 64];
      #pragma unroll
      for (int t = 0; t < 6; ++t) {
        const int o = 16*t + lr;
        const bf16x8 b0 = *(const bf16x8*)&Ws[s][o*96 + lg*8];
        const bf16x8 b1 = *(const bf16x8*)&Ws[s][o*96 + 32 + lg*8];
        const bf16x8 b2 = *(const bf16x8*)&Ws[s][o*96 + 64 + lg*8];
        acc[t] = __builtin_amdgcn_mfma_f32_16x16x32_bf16(a0, b0, acc[t], 0, 0, 0);
        acc[t] = __builtin_amdgcn_mfma_f32_16x16x32_bf16(a1, b1, acc[t], 0, 0, 0);
        acc[t] = __builtin_amdgcn_mfma_f32_16x16x32_bf16(a2, b2, acc[t], 0, 0, 0);
      }
    }
    float* og = out + (size_t)blk * 4704;
    #pragma unroll
    for (int t = 0; t < 6; ++t) {
      const int co = 16*t + lr;
      const float bb = bias_all[co];
      #pragma unroll
      for (int r = 0; r < 4; ++r) {
        const int tok = 16*w + lg*4 + r;
        if (tok < NTOK) og[tok*96 + co] = acc[t][r] + bb;
      }
    }
  }
}

extern "C" void kernel_launch(void* const* d_in, const int* in_sizes, int n_in,
                              void* d_out, int out_size, void* d_ws, size_t ws_size,
                              hipStream_t stream)
{
  const float* x      = (const float*)d_in[0];
  const float* rpbt   = (const float*)d_in[1];
  const float* wq     = (const float*)d_in[2];
  const float* bq     = (const float*)d_in[3];
  const float* wk     = (const float*)d_in[4];
  const float* bk     = (const float*)d_in[5];
  const float* wv     = (const float*)d_in[6];
  const float* bv     = (const float*)d_in[7];
  const float* w_ps   = (const float*)d_in[8];
  const float* b_ps   = (const float*)d_in[9];
  const float* wq_sp  = (const float*)d_in[10];
  const float* wk_sp  = (const float*)d_in[11];
  const float* w_pc   = (const float*)d_in[12];
  const float* b_pc   = (const float*)d_in[13];
  const float* conv1  = (const float*)d_in[14];
  const float* conv2  = (const float*)d_in[15];
  const float* w_proj = (const float*)d_in[16];
  const float* b_proj = (const float*)d_in[17];

  unsigned short* wsS = (unsigned short*)d_ws;
  float* wsB = (float*)((char*)d_ws + (size_t)2*73728);

  prep_weights<<<80, 256, 0, stream>>>(wq, wk, wv, wq_sp, wk_sp, w_ps, b_ps,
                                       w_pc, b_pc, w_proj, b_proj, wsS, wsB);

  const int nblk = in_sizes[0] / (NTOK*CDIM);   // 8192 windows
  winattn_mfma<<<nblk, 256, 0, stream>>>(x, rpbt, bq, bk, bv, conv1, conv2,
      wsS, wsS + 27648, wsS + 46080, wsS + 55296, wsS + 64512, wsB,
      (float*)d_out);
}

// Round 2
// 871.258 us; speedup vs baseline: 4.3836x; 1.8324x over previous
//
#include <hip/hip_runtime.h>

#define NTOK 49
#define CDIM 96
#define NH   3
#define HD   32

typedef __bf16 bf16x8 __attribute__((ext_vector_type(8)));
typedef float f32x4 __attribute__((ext_vector_type(4)));

__device__ __forceinline__ unsigned short f2bf(float f) {
  union { float f; unsigned u; } v; v.f = f;
  unsigned r = v.u + 0x7FFFu + ((v.u >> 16) & 1u);   // RNE
  return (unsigned short)(r >> 16);
}
__device__ __forceinline__ float bf2f(unsigned short h) {
  union { unsigned u; float f; } v; v.u = ((unsigned)h) << 16;
  return v.f;
}

// ---------------------------------------------------------------------------
// Prep kernel: fp32 weights in -> fused/transposed bf16 weights in d_ws.
//   [     0..27648)  W1cat_t [288][96] = [wq_sp | wk_sp | wv]^T
//   [ 27648..46080)  W2cat_t [192][96] = per-head [q|k] slices of wq,wk
//   [ 46080..55296)  W1b_t   [96][96]  = (w_ps @ Wp_top)^T
//   [ 55296..64512)  W2b_t   [96][96]  = (w_pc @ Wp_bot)^T
//   [ 64512..73728)  Wpb_t   [96][96]  = Wp_bot^T
//   float[96] @ byte 147456: bias_all = b_ps@Wp_top + b_pc@Wp_bot + b_proj
// ---------------------------------------------------------------------------
__global__ void prep_weights(const float* __restrict__ wq,
                             const float* __restrict__ wk,
                             const float* __restrict__ wv,
                             const float* __restrict__ wq_sp,
                             const float* __restrict__ wk_sp,
                             const float* __restrict__ w_ps,
                             const float* __restrict__ b_ps,
                             const float* __restrict__ w_pc,
                             const float* __restrict__ b_pc,
                             const float* __restrict__ w_proj,
                             const float* __restrict__ b_proj,
                             unsigned short* __restrict__ wsS,
                             float* __restrict__ wsB)
{
  const int g0 = blockIdx.x * blockDim.x + threadIdx.x;
  const int gs = gridDim.x * blockDim.x;
  const int TOT = 73728 + 96;
  for (int idx = g0; idx < TOT; idx += gs) {
    if (idx < 27648) {
      int o = idx / 96, i = idx % 96;
      float v;
      if (o < 96)       v = wq_sp[i*96 + o];
      else if (o < 192) v = wk_sp[i*96 + (o-96)];
      else              v = wv  [i*96 + (o-192)];
      wsS[idx] = f2bf(v);
    } else if (idx < 46080) {
      int j = idx - 27648, o = j / 96, i = j % 96;
      int h = o >> 6, cc = o & 63;
      wsS[idx] = f2bf((cc < 32) ? wq[i*96 + h*32 + cc] : wk[i*96 + h*32 + (cc-32)]);
    } else if (idx < 55296) {
      int j = idx - 46080, o = j / 96, i = j % 96;
      float a = 0.f;
      for (int k = 0; k < 96; ++k) a += w_ps[i*96+k] * w_proj[k*96+o];
      wsS[idx] = f2bf(a);
    } else if (idx < 64512) {
      int j = idx - 55296, o = j / 96, i = j % 96;
      float a = 0.f;
      for (int k = 0; k < 96; ++k) a += w_pc[i*96+k] * w_proj[(96+k)*96+o];
      wsS[idx] = f2bf(a);
    } else if (idx < 73728) {
      int j = idx - 64512, o = j / 96, i = j % 96;
      wsS[idx] = f2bf(w_proj[(96+i)*96 + o]);
    } else {
      int o = idx - 73728;
      float a = b_proj[o];
      for (int k = 0; k < 96; ++k) {
        a += b_ps[k] * w_proj[k*96+o];
        a += b_pc[k] * w_proj[(96+k)*96+o];
      }
      wsB[o] = a;
    }
  }
}

// ---------------------------------------------------------------------------
// Fused window kernel, round 2: all matmul-shaped stages on MFMA, 3 blocks/CU.
// LDS (shorts), total 26864 = 53728 B -> 3 blocks/CU:
//   X_O  = 0     [49][96]       x  -> q -> sp        (alias; per-wave own rows)
//   V_O  = 4704  [49][96]       v
//   QS_O = 9408  [49][98]       qs (stride 98!) -> xc [49][96]
//   KS_O = 14216 [49][98]       ks (stride 98!) -> gelu -> outp [49][96]
//   K_O  = 19024 [49][96]       rn float[192] (during C'-D) -> k
//   SC_O = 23728 3136           cattn [96][32] -> probs [49][64] (pad cols 0)
// qs/ks stride 98 => token-gathers for D hit ~2-way banks (49 dw ≡ 17 mod 32).
// Overreads past slot ends land inside sm[] (finite bf16) and only feed
// write-guarded outputs; PV A-fragment rows clamped to 48.
// ---------------------------------------------------------------------------
__global__ __launch_bounds__(256, 3) void winattn_mfma3(
    const float* __restrict__ x,
    const float* __restrict__ rpb,      // [169][3]
    const float* __restrict__ bq,
    const float* __restrict__ bk,
    const float* __restrict__ bv,
    const float* __restrict__ conv1w,   // [9][96]
    const float* __restrict__ conv2w,   // [9][96]
    const unsigned short* __restrict__ wcat1,    // [288][96] bf16
    const unsigned short* __restrict__ wcat2,    // [192][96] bf16
    const unsigned short* __restrict__ w1b,      // [96][96] bf16
    const unsigned short* __restrict__ w2b,      // [96][96] bf16
    const unsigned short* __restrict__ wpb,      // [96][96] bf16
    const float* __restrict__ bias_all,          // [96]
    float* __restrict__ out)
{
  __shared__ __align__(16) unsigned short sm[26864];   // 53728 B
  const int tid = threadIdx.x;
  const int blk = blockIdx.x;
  enum { X_O = 0, V_O = 4704, QS_O = 9408, KS_O = 14216,
         K_O = 19024, SC_O = 23728 };
  const float SCALE = 0.17677669529663687f;

  const int w  = tid >> 6;    // wave id = token m-tile
  const int l  = tid & 63;
  const int lr = l & 15;      // fragment row / col index
  const int lg = l >> 4;      // lane group (k-slice / D row group)
  float* const rn = (float*)&sm[K_O];   // [192]: qs norms, then ks norms

  // ---- A: load x (fp32 -> bf16 LDS) ----
  {
    const float* xg = x + (size_t)blk * 4704;
    for (int i = tid; i < 1176; i += 256) {
      const float4 v = *(const float4*)&xg[i*4];
      union { unsigned short s[4]; uint2 u; } p;
      p.s[0] = f2bf(v.x); p.s[1] = f2bf(v.y); p.s[2] = f2bf(v.z); p.s[3] = f2bf(v.w);
      *(uint2*)&sm[X_O + i*4] = p.u;
    }
  }
  __syncthreads();

  // ---- B (MFMA): [qs|ks|v] = x @ Wcat1 (+bv on v) ----
  {
    const int xrow = X_O + (16*w + lr)*96 + lg*8;
    const bf16x8 a0 = *(const bf16x8*)&sm[xrow];
    const bf16x8 a1 = *(const bf16x8*)&sm[xrow + 32];
    const bf16x8 a2 = *(const bf16x8*)&sm[xrow + 64];
    for (int t = 0; t < 18; ++t) {
      const int c = 16*t + lr;
      const bf16x8 b0 = *(const bf16x8*)&wcat1[c*96 + lg*8];
      const bf16x8 b1 = *(const bf16x8*)&wcat1[c*96 + 32 + lg*8];
      const bf16x8 b2 = *(const bf16x8*)&wcat1[c*96 + 64 + lg*8];
      f32x4 acc = {0.f, 0.f, 0.f, 0.f};
      acc = __builtin_amdgcn_mfma_f32_16x16x32_bf16(a0, b0, acc, 0, 0, 0);
      acc = __builtin_amdgcn_mfma_f32_16x16x32_bf16(a1, b1, acc, 0, 0, 0);
      acc = __builtin_amdgcn_mfma_f32_16x16x32_bf16(a2, b2, acc, 0, 0, 0);
      int base, col, strd; float bias = 0.f;
      if (t < 6)       { base = QS_O; col = c;       strd = 98; }
      else if (t < 12) { base = KS_O; col = c - 96;  strd = 98; }
      else             { base = V_O;  col = c - 192; strd = 96; bias = bv[c-192]; }
      #pragma unroll
      for (int r = 0; r < 4; ++r) {
        const int tok = 16*w + lg*4 + r;
        if (tok < NTOK) sm[base + tok*strd + col] = f2bf(acc[r] + bias);
      }
    }
  }
  __syncthreads();

  // ---- C': channel norms of qs, ks (stored f32, folded into D) ----
  if (tid < 192) {
    const int c    = (tid < 96) ? tid : tid - 96;
    const int base = (tid < 96) ? QS_O : KS_O;
    float ss = 0.f;
    for (int n = 0; n < NTOK; ++n) { const float v = bf2f(sm[base + n*98 + c]); ss += v*v; }
    rn[tid] = 1.0f / fmaxf(sqrtf(ss), 1e-12f);
  }
  __syncthreads();

  // ---- D (MFMA): cattn logits [96][32] via token-gathered fragments ----
  {
    for (int jb = 0; jb < 3; ++jb) {
      const int job = w*3 + jb, rt = job >> 1, ct = job & 1, h = rt >> 1;
      const int qc = h*32 + 16*ct + lr;          // qs channel for this lane
      union { unsigned short u[8]; bf16x8 v; } a0u, a1u, b0u, b1u;
      #pragma unroll
      for (int j = 0; j < 8; ++j) {
        const int k0 = lg*8 + j, k1 = 32 + k0;
        a0u.u[j] = sm[KS_O + k0*98 + 16*rt + lr];
        b0u.u[j] = sm[QS_O + k0*98 + qc];
        a1u.u[j] = (k1 < NTOK) ? sm[KS_O + k1*98 + 16*rt + lr] : (unsigned short)0;
        b1u.u[j] = (k1 < NTOK) ? sm[QS_O + k1*98 + qc] : (unsigned short)0;
      }
      f32x4 acc = {0.f, 0.f, 0.f, 0.f};
      acc = __builtin_amdgcn_mfma_f32_16x16x32_bf16(a0u.v, b0u.v, acc, 0, 0, 0);
      acc = __builtin_amdgcn_mfma_f32_16x16x32_bf16(a1u.v, b1u.v, acc, 0, 0, 0);
      const float rq = rn[qc];
      #pragma unroll
      for (int r = 0; r < 4; ++r) {
        const int dq = 16*rt + lg*4 + r;
        sm[SC_O + dq*32 + 16*ct + lr] = f2bf(acc[r] * rq * rn[96 + dq] * SCALE);
      }
    }
  }
  __syncthreads();

  // ---- I (MFMA): q,k = x @ Wcat2; q into X slot (own rows only) ----
  {
    const int xrow = X_O + (16*w + lr)*96 + lg*8;
    const bf16x8 a0 = *(const bf16x8*)&sm[xrow];
    const bf16x8 a1 = *(const bf16x8*)&sm[xrow + 32];
    const bf16x8 a2 = *(const bf16x8*)&sm[xrow + 64];
    for (int t = 0; t < 12; ++t) {
      const int c = 16*t + lr;
      const bf16x8 b0 = *(const bf16x8*)&wcat2[c*96 + lg*8];
      const bf16x8 b1 = *(const bf16x8*)&wcat2[c*96 + 32 + lg*8];
      const bf16x8 b2 = *(const bf16x8*)&wcat2[c*96 + 64 + lg*8];
      f32x4 acc = {0.f, 0.f, 0.f, 0.f};
      acc = __builtin_amdgcn_mfma_f32_16x16x32_bf16(a0, b0, acc, 0, 0, 0);
      acc = __builtin_amdgcn_mfma_f32_16x16x32_bf16(a1, b1, acc, 0, 0, 0);
      acc = __builtin_amdgcn_mfma_f32_16x16x32_bf16(a2, b2, acc, 0, 0, 0);
      const int h = t >> 2;
      const bool isq = (t & 3) < 2;
      const int cc = (t & 1)*16 + lr;            // 0..31 within q or k half
      const float bias = isq ? bq[h*32 + cc] : bk[h*32 + cc];
      const int dst = (isq ? X_O : K_O) + h*32 + cc;
      #pragma unroll
      for (int r = 0; r < 4; ++r) {
        const int tok = 16*w + lg*4 + r;
        if (tok < NTOK) sm[dst + tok*96] = f2bf(acc[r] + bias);
      }
    }
  }
  // ---- E: softmax over e (96 rows of 32), bank-staggered column order ----
  if (tid < 96) {
    const int base = SC_O + tid*32;
    const int off = (tid * 5) & 31;
    float m = -1e30f;
    for (int jj = 0; jj < 32; ++jj) { const int j = (jj + off) & 31;
      m = fmaxf(m, bf2f(sm[base + j])); }
    float s = 0.f;
    for (int jj = 0; jj < 32; ++jj) { const int j = (jj + off) & 31;
      s += __expf(bf2f(sm[base + j]) - m); }
    const float inv = 1.0f / s;
    for (int jj = 0; jj < 32; ++jj) { const int j = (jj + off) & 31;
      sm[base + j] = f2bf(__expf(bf2f(sm[base + j]) - m) * inv); }
  }
  __syncthreads();

  // ---- F (MFMA): xc[n][dq] = cattn @ V -> QS slot (stride 96) ----
  {
    for (int ctile = 0; ctile < 6; ++ctile) {
      const int h = ctile >> 1;
      const bf16x8 av  = *(const bf16x8*)&sm[V_O + (16*w + lr)*96 + h*32 + lg*8];
      const bf16x8 bc  = *(const bf16x8*)&sm[SC_O + (16*ctile + lr)*32 + lg*8];
      f32x4 acc = {0.f, 0.f, 0.f, 0.f};
      acc = __builtin_amdgcn_mfma_f32_16x16x32_bf16(av, bc, acc, 0, 0, 0);
      #pragma unroll
      for (int r = 0; r < 4; ++r) {
        const int tok = 16*w + lg*4 + r;
        if (tok < NTOK) sm[QS_O + tok*96 + 16*ctile + lr] = f2bf(acc[r]);
      }
    }
  }
  // ---- G: conv1 + exact GELU -> KS slot (stride 96), 8-ch vectorized ----
  for (int idx = tid; idx < 588; idx += 256) {
    const int n = idx / 12, c0 = (idx % 12) * 8;
    const int y = n / 7, xx = n % 7;
    float a[8];
    #pragma unroll
    for (int j = 0; j < 8; ++j) a[j] = 0.f;
    #pragma unroll
    for (int dy = -1; dy <= 1; ++dy) {
      const int yy = y + dy;
      if (yy < 0 || yy >= 7) continue;
      #pragma unroll
      for (int dx = -1; dx <= 1; ++dx) {
        const int x2 = xx + dx;
        if (x2 < 0 || x2 >= 7) continue;
        union { bf16x8 v; unsigned short u[8]; } iv;
        iv.v = *(const bf16x8*)&sm[V_O + (yy*7 + x2)*96 + c0];
        const float* wp = conv1w + ((dy+1)*3 + (dx+1))*96 + c0;
        #pragma unroll
        for (int j = 0; j < 8; ++j) a[j] += bf2f(iv.u[j]) * wp[j];
      }
    }
    union { unsigned short u[8]; bf16x8 v; } ov;
    #pragma unroll
    for (int j = 0; j < 8; ++j) {
      const float g = a[j];
      ov.u[j] = f2bf(0.5f * g * (1.0f + erff(g * 0.70710678118654752f)));
    }
    *(bf16x8*)&sm[KS_O + n*96 + c0] = ov.v;
  }
  __syncthreads();

  // ---- H: conv2 -> regs; zero probs pad cols; write back ----
  float hov[3][8];
  {
    #pragma unroll
    for (int it = 0; it < 3; ++it) {
      const int e = tid + it*256;
      #pragma unroll
      for (int j = 0; j < 8; ++j) hov[it][j] = 0.f;
      if (e < 588) {
        const int n = e / 12, c0 = (e % 12) * 8;
        const int y = n / 7, xx = n % 7;
        #pragma unroll
        for (int dy = -1; dy <= 1; ++dy) {
          const int yy = y + dy;
          if (yy < 0 || yy >= 7) continue;
          #pragma unroll
          for (int dx = -1; dx <= 1; ++dx) {
            const int x2 = xx + dx;
            if (x2 < 0 || x2 >= 7) continue;
            union { bf16x8 v; unsigned short u[8]; } iv;
            iv.v = *(const bf16x8*)&sm[KS_O + (yy*7 + x2)*96 + c0];
            const float* wp = conv2w + ((dy+1)*3 + (dx+1))*96 + c0;
            #pragma unroll
            for (int j = 0; j < 8; ++j) hov[it][j] += bf2f(iv.u[j]) * wp[j];
          }
        }
      }
    }
    for (int zi = tid; zi < 735; zi += 256)       // probs pad cols 49..63 := 0
      sm[SC_O + (zi/15)*64 + 49 + zi%15] = 0;
  }
  __syncthreads();
  {
    #pragma unroll
    for (int it = 0; it < 3; ++it) {
      const int e = tid + it*256;
      if (e < 588) {
        const int n = e / 12, c0 = (e % 12) * 8;
        union { unsigned short u[8]; bf16x8 v; } ov;
        #pragma unroll
        for (int j = 0; j < 8; ++j) ov.u[j] = f2bf(hov[it][j]);
        *(bf16x8*)&sm[KS_O + n*96 + c0] = ov.v;
      }
    }
  }
  __syncthreads();

  // ---- J: spatial attention per head (MFMA QK^T and PV) ----
  for (int h = 0; h < NH; ++h) {
    {
      const bf16x8 aq = *(const bf16x8*)&sm[X_O + (16*w + lr)*96 + h*32 + lg*8];
      #pragma unroll
      for (int nt = 0; nt < 4; ++nt) {
        const bf16x8 bk8 = *(const bf16x8*)&sm[K_O + (16*nt + lr)*96 + h*32 + lg*8];
        f32x4 acc = {0.f, 0.f, 0.f, 0.f};
        acc = __builtin_amdgcn_mfma_f32_16x16x32_bf16(aq, bk8, acc, 0, 0, 0);
        #pragma unroll
        for (int r = 0; r < 4; ++r) {
          const int row = 16*w + lg*4 + r;
          const int col = 16*nt + lr;
          if (row < NTOK && col < NTOK) {
            const int ridx = (row/7 - col/7 + 6)*13 + (row%7 - col%7 + 6);
            sm[SC_O + row*64 + col] = f2bf(acc[r] * SCALE + rpb[ridx*NH + h]);
          }
        }
      }
    }
    __syncthreads();
    // softmax: 4 threads/row, shfl-combined, row-rotated column order
    if (tid < 196) {
      const int row = tid >> 2, p = tid & 3;
      const int cS = p * 13;
      const int cnt = (p == 3) ? 10 : 13;
      const int ro = row % cnt;
      const int base = SC_O + row*64 + cS;
      float m = -1e30f;
      for (int i = 0; i < cnt; ++i) {
        int j = i + ro; if (j >= cnt) j -= cnt;
        m = fmaxf(m, bf2f(sm[base + j]));
      }
      m = fmaxf(m, __shfl_xor(m, 1, 4));
      m = fmaxf(m, __shfl_xor(m, 2, 4));
      float s = 0.f;
      for (int i = 0; i < cnt; ++i) {
        int j = i + ro; if (j >= cnt) j -= cnt;
        s += __expf(bf2f(sm[base + j]) - m);
      }
      s += __shfl_xor(s, 1, 4);
      s += __shfl_xor(s, 2, 4);
      const float inv = 1.0f / s;
      for (int i = 0; i < cnt; ++i) {
        int j = i + ro; if (j >= cnt) j -= cnt;
        sm[base + j] = f2bf(__expf(bf2f(sm[base + j]) - m) * inv);
      }
    }
    __syncthreads();
    {
      const int prow = (16*w + lr < 48) ? (16*w + lr) : 48;   // clamp pad rows
      const bf16x8 ap0 = *(const bf16x8*)&sm[SC_O + prow*64 + lg*8];
      const bf16x8 ap1 = *(const bf16x8*)&sm[SC_O + prow*64 + 32 + lg*8];
      #pragma unroll
      for (int nt = 0; nt < 2; ++nt) {
        f32x4 acc = {0.f, 0.f, 0.f, 0.f};
        union { unsigned short u[8]; bf16x8 v; } cv;
        #pragma unroll
        for (int j = 0; j < 8; ++j)
          cv.u[j] = sm[V_O + (lg*8 + j)*96 + h*32 + 16*nt + lr];
        acc = __builtin_amdgcn_mfma_f32_16x16x32_bf16(ap0, cv.v, acc, 0, 0, 0);
        #pragma unroll
        for (int j = 0; j < 8; ++j)
          cv.u[j] = sm[V_O + (32 + lg*8 + j)*96 + h*32 + 16*nt + lr];
        acc = __builtin_amdgcn_mfma_f32_16x16x32_bf16(ap1, cv.v, acc, 0, 0, 0);
        #pragma unroll
        for (int r = 0; r < 4; ++r) {
          const int tok = 16*w + lg*4 + r;
          if (tok < NTOK) sm[X_O + tok*96 + h*32 + 16*nt + lr] = f2bf(acc[r]);
        }
      }
    }
    __syncthreads();
  }

  // ---- K (MFMA): out = sp@W1b + xc@W2b + outp@Wpb + bias_all ----
  {
    f32x4 acc[6];
    #pragma unroll
    for (int t = 0; t < 6; ++t) acc[t] = (f32x4){0.f, 0.f, 0.f, 0.f};
    const int Ao[3] = { X_O, QS_O, KS_O };
    const unsigned short* const Ws[3] = { w1b, w2b, wpb };
    #pragma unroll
    for (int s = 0; s < 3; ++s) {
      const int arow = Ao[s] + (16*w + lr)*96 + lg*8;
      const bf16x8 a0 = *(const bf16x8*)&sm[arow];
      const bf16x8 a1 = *(const bf16x8*)&sm[arow + 32];
      const bf16x8 a2 = *(const bf16x8*)&sm[arow + 64];
      #pragma unroll
      for (int t = 0; t < 6; ++t) {
        const int o = 16*t + lr;
        const bf16x8 b0 = *(const bf16x8*)&Ws[s][o*96 + lg*8];
        const bf16x8 b1 = *(const bf16x8*)&Ws[s][o*96 + 32 + lg*8];
        const bf16x8 b2 = *(const bf16x8*)&Ws[s][o*96 + 64 + lg*8];
        acc[t] = __builtin_amdgcn_mfma_f32_16x16x32_bf16(a0, b0, acc[t], 0, 0, 0);
        acc[t] = __builtin_amdgcn_mfma_f32_16x16x32_bf16(a1, b1, acc[t], 0, 0, 0);
        acc[t] = __builtin_amdgcn_mfma_f32_16x16x32_bf16(a2, b2, acc[t], 0, 0, 0);
      }
    }
    float* og = out + (size_t)blk * 4704;
    #pragma unroll
    for (int t = 0; t < 6; ++t) {
      const int co = 16*t + lr;
      const float bb = bias_all[co];
      #pragma unroll
      for (int r = 0; r < 4; ++r) {
        const int tok = 16*w + lg*4 + r;
        if (tok < NTOK) og[tok*96 + co] = acc[t][r] + bb;
      }
    }
  }
}

extern "C" void kernel_launch(void* const* d_in, const int* in_sizes, int n_in,
                              void* d_out, int out_size, void* d_ws, size_t ws_size,
                              hipStream_t stream)
{
  const float* x      = (const float*)d_in[0];
  const float* rpbt   = (const float*)d_in[1];
  const float* wq     = (const float*)d_in[2];
  const float* bq     = (const float*)d_in[3];
  const float* wk     = (const float*)d_in[4];
  const float* bk     = (const float*)d_in[5];
  const float* wv     = (const float*)d_in[6];
  const float* bv     = (const float*)d_in[7];
  const float* w_ps   = (const float*)d_in[8];
  const float* b_ps   = (const float*)d_in[9];
  const float* wq_sp  = (const float*)d_in[10];
  const float* wk_sp  = (const float*)d_in[11];
  const float* w_pc   = (const float*)d_in[12];
  const float* b_pc   = (const float*)d_in[13];
  const float* conv1  = (const float*)d_in[14];
  const float* conv2  = (const float*)d_in[15];
  const float* w_proj = (const float*)d_in[16];
  const float* b_proj = (const float*)d_in[17];

  unsigned short* wsS = (unsigned short*)d_ws;
  float* wsB = (float*)((char*)d_ws + (size_t)2*73728);

  prep_weights<<<80, 256, 0, stream>>>(wq, wk, wv, wq_sp, wk_sp, w_ps, b_ps,
                                       w_pc, b_pc, w_proj, b_proj, wsS, wsB);

  const int nblk = in_sizes[0] / (NTOK*CDIM);   // 8192 windows
  winattn_mfma3<<<nblk, 256, 0, stream>>>(x, rpbt, bq, bk, bv, conv1, conv2,
      wsS, wsS + 27648, wsS + 46080, wsS + 55296, wsS + 64512, wsB,
      (float*)d_out);
}